// Round 9
// baseline (713.863 us; speedup 1.0000x reference)
//
#include <hip/hip_runtime.h>
#include <math.h>

#define N_NODES 32768
#define N_EDGES 491520
#define F_IN    11
#define H       64
#define G_GRAPHS 2048
#define NN_PER_G 16
#define R_REACT 1024
#define L_LAYERS 4
#define EIN     129   // 2H+1
#define NIN     139   // 2H+F
#define NPBLK   32    // nodes per k_edge7 block

typedef __attribute__((ext_vector_type(8))) short short8;
typedef __attribute__((ext_vector_type(4))) float f32x4;

__device__ __forceinline__ float silu_f(float x) {
    return x * __builtin_amdgcn_rcpf(1.0f + __expf(-x));
}
__device__ __forceinline__ void atomAddF(float* p, float v) {
    unsafeAtomicAdd(p, v);
}
__device__ __forceinline__ float bf2f(unsigned short b) {
    union { float f; unsigned u; } v; v.u = ((unsigned)b) << 16;
    return v.f;
}
__device__ __forceinline__ unsigned short f2bf(float x) {   // RNE
    union { float f; unsigned u; } v; v.f = x;
    unsigned r = v.u + 0x7FFFu + ((v.u >> 16) & 1u);
    return (unsigned short)(r >> 16);
}
// RNE split (weights, cold path)
__device__ __forceinline__ void splitbf(float x, unsigned short& hi, unsigned short& lo) {
    hi = f2bf(x);
    lo = f2bf(x - bf2f(hi));
}
// truncation split (hot path; R4-validated absmax 3e-5)
__device__ __forceinline__ void splitbf_t(float x, unsigned short& hi, unsigned short& lo) {
    union { float f; unsigned u; } v; v.f = x;
    hi = (unsigned short)(v.u >> 16);
    union { float f; unsigned u; } w; w.f = x - bf2f(hi);
    lo = (unsigned short)(w.u >> 16);
}

// ---------------- embed ----------------
__global__ __launch_bounds__(256) void k_embed(
        const float* __restrict__ h0, const float* __restrict__ emb_w,
        const float* __restrict__ emb_b, float* __restrict__ h) {
    int tid = blockIdx.x * 256 + threadIdx.x;
    int n = tid >> 6, j = tid & 63;
    float acc = emb_b[j];
#pragma unroll
    for (int k = 0; k < F_IN; ++k)
        acc += h0[n * F_IN + k] * emb_w[k * H + j];
    h[tid] = acc;
}

// ---------------- radial ----------------
__global__ __launch_bounds__(256) void k_radial(
        const int* __restrict__ edges, const float* __restrict__ pos,
        float* __restrict__ radial) {
    int e = blockIdx.x * 256 + threadIdx.x;
    int r = edges[e], c = edges[N_EDGES + e];
    float dx = pos[r * 3 + 0] - pos[c * 3 + 0];
    float dy = pos[r * 3 + 1] - pos[c * 3 + 1];
    float dz = pos[r * 3 + 2] - pos[c * 3 + 2];
    radial[e] = dx * dx + dy * dy + dz * dz;
}

// ---------------- CSR build ----------------
__global__ __launch_bounds__(256) void k_hist(
        const int* __restrict__ edges, int* __restrict__ deg) {
    int e = blockIdx.x * 256 + threadIdx.x;
    atomicAdd(&deg[edges[e]], 1);
}

__global__ __launch_bounds__(128) void k_scan_blk(
        const int* __restrict__ deg, int* __restrict__ off,
        int* __restrict__ bsum) {
    __shared__ int sd[128];
    int b = blockIdx.x;
    sd[threadIdx.x] = deg[b * 128 + threadIdx.x];
    __syncthreads();
    if (threadIdx.x == 0) {
        int s = 0;
        for (int i = 0; i < 128; ++i) { int d = sd[i]; sd[i] = s; s += d; }
        bsum[b] = s;
    }
    __syncthreads();
    off[b * 128 + threadIdx.x] = sd[threadIdx.x];
}

__global__ __launch_bounds__(256) void k_scan_top(
        const int* __restrict__ bsum, int* __restrict__ bbase) {
    __shared__ int sb[256];
    sb[threadIdx.x] = bsum[threadIdx.x];
    __syncthreads();
    if (threadIdx.x == 0) {
        int s = 0;
        for (int i = 0; i < 256; ++i) { int d = sb[i]; sb[i] = s; s += d; }
    }
    __syncthreads();
    bbase[threadIdx.x] = sb[threadIdx.x];
}

__global__ __launch_bounds__(256) void k_cursor(
        const int* __restrict__ off, const int* __restrict__ bbase,
        int* __restrict__ nstart, int* __restrict__ cursor) {
    int n = blockIdx.x * 256 + threadIdx.x;
    int ns = off[n] + bbase[n >> 7];
    nstart[n] = ns;
    cursor[n] = ns;
    if (n == 0) nstart[N_NODES] = N_EDGES;
}

__global__ __launch_bounds__(256) void k_fill(
        const int* __restrict__ edges, const float* __restrict__ radial,
        const float* __restrict__ emask, int* __restrict__ cursor,
        int* __restrict__ csrP, float* __restrict__ csrR,
        float* __restrict__ csrM) {
    int e = blockIdx.x * 256 + threadIdx.x;
    int r = edges[e];
    int pos = atomicAdd(&cursor[r], 1);
    csrP[pos] = edges[N_EDGES + e] | ((r & (NPBLK - 1)) << 16);  // col | row_local
    csrR[pos] = radial[e];
    csrM[pos] = emask[e];
}

// ---------------- node projection: LDS-staged weights, 4 waves ----------
#define KP_P 136
__global__ __launch_bounds__(256, 2) void k_nodeproj_m(
        const float* __restrict__ h, const float* __restrict__ W1,
        const float* __restrict__ b1,
        float* __restrict__ PA, float* __restrict__ PB) {
    const int tid = threadIdx.x;
    const int lane = tid & 63, wave = tid >> 6;
    const int quad = lane >> 4, m16 = lane & 15;

    __shared__ unsigned short Whi[64 * KP_P], Wlo[64 * KP_P];
    for (int i = tid; i < 64 * KP_P; i += 256) {
        int k = i >> 6, n = i & 63;
        float w = (k < 128) ? W1[k * H + n] : 0.0f;
        unsigned short hi, lo; splitbf(w, hi, lo);
        Whi[n * KP_P + k] = hi;
        Wlo[n * KP_P + k] = lo;
    }
    float b1v[4];
#pragma unroll
    for (int nt = 0; nt < 4; ++nt) b1v[nt] = b1[nt * 16 + m16];
    __syncthreads();

    for (int t = 0; t < 2; ++t) {
        const int nb = (blockIdx.x * 8 + wave * 2 + t) * 16;
        const float* hp = h + (nb + m16) * H + quad * 8;
        float av[16];
        *(float4*)&av[0]  = *(const float4*)(hp + 0);
        *(float4*)&av[4]  = *(const float4*)(hp + 4);
        *(float4*)&av[8]  = *(const float4*)(hp + 32);
        *(float4*)&av[12] = *(const float4*)(hp + 36);
        short8 Ah0, Ah1, Al0, Al1;
#pragma unroll
        for (int j = 0; j < 8; ++j) {
            unsigned short hi, lo;
            splitbf_t(av[j], hi, lo);     Ah0[j] = (short)hi; Al0[j] = (short)lo;
            splitbf_t(av[8 + j], hi, lo); Ah1[j] = (short)hi; Al1[j] = (short)lo;
        }
        f32x4 acc[8];
#pragma unroll
        for (int nt = 0; nt < 8; ++nt) {
            const int col = (nt & 3) * 16 + m16;
            const int kb  = (nt >= 4 ? 64 : 0) + quad * 8;
            const unsigned short* ch = &Whi[col * KP_P + kb];
            const unsigned short* cl = &Wlo[col * KP_P + kb];
            f32x4 a = {0.0f, 0.0f, 0.0f, 0.0f};
            short8 bh0 = *(const short8*)(ch +  0);
            short8 bh1 = *(const short8*)(ch + 32);
            short8 bl0 = *(const short8*)(cl +  0);
            short8 bl1 = *(const short8*)(cl + 32);
            a = __builtin_amdgcn_mfma_f32_16x16x32_bf16(Ah0, bh0, a, 0, 0, 0);
            a = __builtin_amdgcn_mfma_f32_16x16x32_bf16(Ah1, bh1, a, 0, 0, 0);
            a = __builtin_amdgcn_mfma_f32_16x16x32_bf16(Ah0, bl0, a, 0, 0, 0);
            a = __builtin_amdgcn_mfma_f32_16x16x32_bf16(Ah1, bl1, a, 0, 0, 0);
            a = __builtin_amdgcn_mfma_f32_16x16x32_bf16(Al0, bh0, a, 0, 0, 0);
            a = __builtin_amdgcn_mfma_f32_16x16x32_bf16(Al1, bh1, a, 0, 0, 0);
            acc[nt] = a;
        }
#pragma unroll
        for (int r4 = 0; r4 < 4; ++r4) {
            const int node = nb + quad * 4 + r4;
#pragma unroll
            for (int nt = 0; nt < 4; ++nt)
                PA[node * H + nt * 16 + m16] = acc[nt][r4] + b1v[nt];
#pragma unroll
            for (int nt = 4; nt < 8; ++nt)
                PB[node * H + (nt - 4) * 16 + m16] = acc[nt][r4];
        }
    }
}

// ---------------- edge MLP v7: PA + W2 in LDS, 4 blocks/CU ---------------
__global__ __launch_bounds__(256, 4) void k_edge7(
        const float* __restrict__ PA, const float* __restrict__ PB,
        const int* __restrict__ nstart, const int* __restrict__ csrP,
        const float* __restrict__ csrR, const float* __restrict__ csrM,
        const float* __restrict__ W1,   // only row 128 (w1c) used
        const float* __restrict__ W2, const float* __restrict__ b2,
        float* __restrict__ agg) {
    const int tid = threadIdx.x;
    const int lane = tid & 63, wave = tid >> 6;
    const int quad = lane >> 4, m16 = lane & 15;
    const int n0 = blockIdx.x * NPBLK;

    __shared__ float aggld[NPBLK * 68];           // 8704 B
    __shared__ float pals[NPBLK * 68];            // 8704 B (PA staged)
    __shared__ unsigned short W2ls_h[64 * 72];    // 9216 B
    __shared__ unsigned short W2ls_l[64 * 72];    // 9216 B

    for (int i = tid; i < NPBLK * 68; i += 256) aggld[i] = 0.0f;
    for (int i = tid; i < NPBLK * 64; i += 256) {
        int n = i >> 6, c = i & 63;
        pals[n * 68 + c] = PA[(n0 + n) * H + c];
    }
    for (int i = tid; i < 64 * 64; i += 256) {
        int k = i >> 6, n = i & 63;
        unsigned short hi, lo; splitbf(W2[k * H + n], hi, lo);
        W2ls_h[n * 72 + k] = hi;
        W2ls_l[n * 72 + k] = lo;
    }
    float w1cr[16];
#pragma unroll
    for (int i = 0; i < 16; ++i) {
        int k = (i < 8) ? (quad * 8 + i) : (32 + quad * 8 + (i - 8));
        w1cr[i] = W1[128 * H + k];
    }
    float b2v[4];
#pragma unroll
    for (int nt = 0; nt < 4; ++nt) b2v[nt] = b2[nt * 16 + m16];

    const int start = nstart[n0];
    const int end   = nstart[n0 + NPBLK];
    __syncthreads();

    const int ntiles = (end - start + 15) >> 4;

    float radA = 0.0f, bvA[16];
    int rlA = 0;
    int rlqA[4]; float mkqA[4];

    int t = wave;
    bool haveA = t < ntiles;
    if (haveA) {
        const int idx = start + t * 16 + m16;
        const int ss = min(idx, N_EDGES - 1);
        const int pk = csrP[ss];
        radA = csrR[ss];
        const int c = pk & 0xFFFF;
        rlA = pk >> 16;
        const int sb = start + t * 16 + quad * 4;
#pragma unroll
        for (int r4 = 0; r4 < 4; ++r4) {
            int s = sb + r4, s2 = min(s, N_EDGES - 1);
            rlqA[r4] = csrP[s2] >> 16;
            mkqA[r4] = (s < end) ? csrM[s2] : 0.0f;
        }
        const float* pbr = PB + c * H + quad * 8;
        *(float4*)&bvA[0]  = *(const float4*)(pbr + 0);
        *(float4*)&bvA[4]  = *(const float4*)(pbr + 4);
        *(float4*)&bvA[8]  = *(const float4*)(pbr + 32);
        *(float4*)&bvA[12] = *(const float4*)(pbr + 36);
    }

    while (haveA) {
        const int tn = t + 4;
        const bool haveB = tn < ntiles;
        float radB = 0.0f, bvB[16];
        int rlB = 0;
        int rlqB[4]; float mkqB[4];
        if (haveB) {
            const int idx = start + tn * 16 + m16;
            const int ss = min(idx, N_EDGES - 1);
            const int pk = csrP[ss];
            radB = csrR[ss];
            const int c = pk & 0xFFFF;
            rlB = pk >> 16;
            const int sb = start + tn * 16 + quad * 4;
#pragma unroll
            for (int r4 = 0; r4 < 4; ++r4) {
                int s = sb + r4, s2 = min(s, N_EDGES - 1);
                rlqB[r4] = csrP[s2] >> 16;
                mkqB[r4] = (s < end) ? csrM[s2] : 0.0f;
            }
            const float* pbr = PB + c * H + quad * 8;
            *(float4*)&bvB[0]  = *(const float4*)(pbr + 0);
            *(float4*)&bvB[4]  = *(const float4*)(pbr + 4);
            *(float4*)&bvB[8]  = *(const float4*)(pbr + 32);
            *(float4*)&bvB[12] = *(const float4*)(pbr + 36);
        }

        // A-side operand from LDS (PA staged; rlA block-local)
        float avA[16];
        const float* pav = &pals[rlA * 68 + quad * 8];
        *(float4*)&avA[0]  = *(const float4*)(pav + 0);
        *(float4*)&avA[4]  = *(const float4*)(pav + 4);
        *(float4*)&avA[8]  = *(const float4*)(pav + 32);
        *(float4*)&avA[12] = *(const float4*)(pav + 36);

        short8 Ah0, Ah1, Al0, Al1;
#pragma unroll
        for (int i = 0; i < 8; ++i) {
            unsigned short hi, lo;
            splitbf_t(silu_f(avA[i] + bvA[i] + radA * w1cr[i]), hi, lo);
            Ah0[i] = (short)hi; Al0[i] = (short)lo;
            splitbf_t(silu_f(avA[8+i] + bvA[8+i] + radA * w1cr[8+i]), hi, lo);
            Ah1[i] = (short)hi; Al1[i] = (short)lo;
        }
        f32x4 acc[4];
#pragma unroll
        for (int nt = 0; nt < 4; ++nt) {
            const unsigned short* ch = &W2ls_h[(nt * 16 + m16) * 72 + quad * 8];
            const unsigned short* cl = &W2ls_l[(nt * 16 + m16) * 72 + quad * 8];
            short8 bh0 = *(const short8*)(ch +  0);
            short8 bh1 = *(const short8*)(ch + 32);
            short8 bl0 = *(const short8*)(cl +  0);
            short8 bl1 = *(const short8*)(cl + 32);
            f32x4 a = {0.0f, 0.0f, 0.0f, 0.0f};
            a = __builtin_amdgcn_mfma_f32_16x16x32_bf16(Ah0, bh0, a, 0, 0, 0);
            a = __builtin_amdgcn_mfma_f32_16x16x32_bf16(Ah1, bh1, a, 0, 0, 0);
            a = __builtin_amdgcn_mfma_f32_16x16x32_bf16(Ah0, bl0, a, 0, 0, 0);
            a = __builtin_amdgcn_mfma_f32_16x16x32_bf16(Ah1, bl1, a, 0, 0, 0);
            a = __builtin_amdgcn_mfma_f32_16x16x32_bf16(Al0, bh0, a, 0, 0, 0);
            a = __builtin_amdgcn_mfma_f32_16x16x32_bf16(Al1, bh1, a, 0, 0, 0);
            acc[nt] = a;
        }

#pragma unroll
        for (int nt = 0; nt < 4; ++nt) {
            float oo[4];
#pragma unroll
            for (int r4 = 0; r4 < 4; ++r4)
                oo[r4] = silu_f(acc[nt][r4] + b2v[nt]) * mkqA[r4];
            int cur = rlqA[0]; float s = oo[0];
#pragma unroll
            for (int r4 = 1; r4 < 4; ++r4) {
                if (rlqA[r4] == cur) { s += oo[r4]; }
                else {
                    atomicAdd(&aggld[cur * 68 + nt * 16 + m16], s);
                    cur = rlqA[r4]; s = oo[r4];
                }
            }
            atomicAdd(&aggld[cur * 68 + nt * 16 + m16], s);
        }

        if (haveB) {
            radA = radB; rlA = rlB;
#pragma unroll
            for (int r4 = 0; r4 < 4; ++r4) { rlqA[r4] = rlqB[r4]; mkqA[r4] = mkqB[r4]; }
#pragma unroll
            for (int i = 0; i < 16; ++i) bvA[i] = bvB[i];
        }
        t = tn; haveA = haveB;
    }

    __syncthreads();
#pragma unroll
    for (int i = tid; i < NPBLK * 16; i += 256) {
        int n = i >> 4, cb = (i & 15) << 2;
        *(float4*)&agg[(n0 + n) * H + cb] = *(const float4*)&aggld[n * 68 + cb];
    }
}

// ---------------- node MLP: LDS-staged weights, 4 waves ------------------
#define KP_N 168
#define KP_2 72
__global__ __launch_bounds__(256, 2) void k_node_m(
        float* __restrict__ h, const float* __restrict__ agg,
        const float* __restrict__ h0,
        const float* __restrict__ W1, const float* __restrict__ b1,
        const float* __restrict__ W2, const float* __restrict__ b2) {
    const int tid = threadIdx.x;
    const int lane = tid & 63, wave = tid >> 6;
    const int quad = lane >> 4, m16 = lane & 15;

    __shared__ unsigned short W1h[64 * KP_N], W1l[64 * KP_N];
    __shared__ unsigned short W2h[64 * KP_2], W2l[64 * KP_2];
    __shared__ float tld[4][16 * 68];

    for (int i = tid; i < 64 * KP_N; i += 256) {
        int k = i >> 6, n = i & 63;
        float w = (k < NIN) ? W1[k * H + n] : 0.0f;
        unsigned short hi, lo; splitbf(w, hi, lo);
        W1h[n * KP_N + k] = hi;
        W1l[n * KP_N + k] = lo;
    }
    for (int i = tid; i < 64 * KP_2; i += 256) {
        int k = i >> 6, n = i & 63;
        float w = (k < H) ? W2[k * H + n] : 0.0f;
        unsigned short hi, lo; splitbf(w, hi, lo);
        W2h[n * KP_2 + k] = hi;
        W2l[n * KP_2 + k] = lo;
    }
    float b1v[4], b2v[4];
#pragma unroll
    for (int nt = 0; nt < 4; ++nt) {
        b1v[nt] = b1[nt * 16 + m16];
        b2v[nt] = b2[nt * 16 + m16];
    }
    __syncthreads();

    for (int t = 0; t < 2; ++t) {
        const int nb = (blockIdx.x * 8 + wave * 2 + t) * 16;
        float a1[5][8];
        const float* hp = h + (nb + m16) * H + quad * 8;
        const float* ap = agg + (nb + m16) * H + quad * 8;
        *(float4*)&a1[0][0] = *(const float4*)(hp + 0);
        *(float4*)&a1[0][4] = *(const float4*)(hp + 4);
        *(float4*)&a1[1][0] = *(const float4*)(hp + 32);
        *(float4*)&a1[1][4] = *(const float4*)(hp + 36);
        *(float4*)&a1[2][0] = *(const float4*)(ap + 0);
        *(float4*)&a1[2][4] = *(const float4*)(ap + 4);
        *(float4*)&a1[3][0] = *(const float4*)(ap + 32);
        *(float4*)&a1[3][4] = *(const float4*)(ap + 36);
        const float* h0p = h0 + (nb + m16) * F_IN;
#pragma unroll
        for (int j = 0; j < 8; ++j) {
            int kk = quad * 8 + j;
            a1[4][j] = (kk < F_IN) ? h0p[kk] : 0.0f;
        }
        short8 A1h[5], A1l[5];
#pragma unroll
        for (int kf = 0; kf < 5; ++kf) {
            short8 ah, al;
#pragma unroll
            for (int j = 0; j < 8; ++j) {
                unsigned short hi, lo; splitbf_t(a1[kf][j], hi, lo);
                ah[j] = (short)hi; al[j] = (short)lo;
            }
            A1h[kf] = ah; A1l[kf] = al;
        }
        f32x4 acc[4];
#pragma unroll
        for (int nt = 0; nt < 4; ++nt) {
            const unsigned short* ch = &W1h[(nt * 16 + m16) * KP_N + quad * 8];
            const unsigned short* cl = &W1l[(nt * 16 + m16) * KP_N + quad * 8];
            f32x4 a = {0.0f, 0.0f, 0.0f, 0.0f};
#pragma unroll
            for (int kf = 0; kf < 5; ++kf) {
                short8 bh = *(const short8*)(ch + kf * 32);
                short8 bl = *(const short8*)(cl + kf * 32);
                a = __builtin_amdgcn_mfma_f32_16x16x32_bf16(A1h[kf], bh, a, 0, 0, 0);
                a = __builtin_amdgcn_mfma_f32_16x16x32_bf16(A1l[kf], bh, a, 0, 0, 0);
                a = __builtin_amdgcn_mfma_f32_16x16x32_bf16(A1h[kf], bl, a, 0, 0, 0);
            }
            acc[nt] = a;
        }
#pragma unroll
        for (int r4 = 0; r4 < 4; ++r4)
#pragma unroll
            for (int nt = 0; nt < 4; ++nt)
                tld[wave][(quad * 4 + r4) * 68 + nt * 16 + m16] =
                    silu_f(acc[nt][r4] + b1v[nt]);
        __syncthreads();
        float a2[16];
        *(float4*)&a2[0]  = *(const float4*)&tld[wave][m16 * 68 + quad * 8 + 0];
        *(float4*)&a2[4]  = *(const float4*)&tld[wave][m16 * 68 + quad * 8 + 4];
        *(float4*)&a2[8]  = *(const float4*)&tld[wave][m16 * 68 + quad * 8 + 32];
        *(float4*)&a2[12] = *(const float4*)&tld[wave][m16 * 68 + quad * 8 + 36];
        short8 A2h0, A2h1, A2l0, A2l1;
#pragma unroll
        for (int j = 0; j < 8; ++j) {
            unsigned short hi, lo;
            splitbf_t(a2[j], hi, lo);     A2h0[j] = (short)hi; A2l0[j] = (short)lo;
            splitbf_t(a2[8+j], hi, lo);   A2h1[j] = (short)hi; A2l1[j] = (short)lo;
        }
        f32x4 acc2[4];
#pragma unroll
        for (int nt = 0; nt < 4; ++nt) {
            const unsigned short* ch = &W2h[(nt * 16 + m16) * KP_2 + quad * 8];
            const unsigned short* cl = &W2l[(nt * 16 + m16) * KP_2 + quad * 8];
            f32x4 a = {0.0f, 0.0f, 0.0f, 0.0f};
            short8 bh0 = *(const short8*)(ch +  0);
            short8 bh1 = *(const short8*)(ch + 32);
            short8 bl0 = *(const short8*)(cl +  0);
            short8 bl1 = *(const short8*)(cl + 32);
            a = __builtin_amdgcn_mfma_f32_16x16x32_bf16(A2h0, bh0, a, 0, 0, 0);
            a = __builtin_amdgcn_mfma_f32_16x16x32_bf16(A2h1, bh1, a, 0, 0, 0);
            a = __builtin_amdgcn_mfma_f32_16x16x32_bf16(A2h0, bl0, a, 0, 0, 0);
            a = __builtin_amdgcn_mfma_f32_16x16x32_bf16(A2h1, bl1, a, 0, 0, 0);
            a = __builtin_amdgcn_mfma_f32_16x16x32_bf16(A2l0, bh0, a, 0, 0, 0);
            a = __builtin_amdgcn_mfma_f32_16x16x32_bf16(A2l1, bh1, a, 0, 0, 0);
            acc2[nt] = a;
        }
#pragma unroll
        for (int r4 = 0; r4 < 4; ++r4) {
            const int node = nb + quad * 4 + r4;
#pragma unroll
            for (int nt = 0; nt < 4; ++nt)
                h[node * H + nt * 16 + m16] = acc2[nt][r4] + b2v[nt];
        }
        __syncthreads();
    }
}

// ---------------- node decoder: LDS-staged weights, 4 waves --------------
__global__ __launch_bounds__(256, 2) void k_dec_m(
        float* __restrict__ h, const float* __restrict__ nmask,
        const float* __restrict__ W1, const float* __restrict__ b1,
        const float* __restrict__ W2, const float* __restrict__ b2) {
    const int tid = threadIdx.x;
    const int lane = tid & 63, wave = tid >> 6;
    const int quad = lane >> 4, m16 = lane & 15;

    __shared__ unsigned short W1h[64 * KP_2], W1l[64 * KP_2];
    __shared__ unsigned short W2h[64 * KP_2], W2l[64 * KP_2];
    __shared__ float tld[4][16 * 68];

    for (int i = tid; i < 64 * KP_2; i += 256) {
        int k = i >> 6, n = i & 63;
        unsigned short hi, lo;
        float w1 = (k < H) ? W1[k * H + n] : 0.0f;
        splitbf(w1, hi, lo);
        W1h[n * KP_2 + k] = hi; W1l[n * KP_2 + k] = lo;
        float w2 = (k < H) ? W2[k * H + n] : 0.0f;
        splitbf(w2, hi, lo);
        W2h[n * KP_2 + k] = hi; W2l[n * KP_2 + k] = lo;
    }
    float b1v[4], b2v[4];
#pragma unroll
    for (int nt = 0; nt < 4; ++nt) {
        b1v[nt] = b1[nt * 16 + m16];
        b2v[nt] = b2[nt * 16 + m16];
    }
    __syncthreads();

    for (int t = 0; t < 2; ++t) {
        const int nb = (blockIdx.x * 8 + wave * 2 + t) * 16;
        const float* hp = h + (nb + m16) * H + quad * 8;
        float av[16];
        *(float4*)&av[0]  = *(const float4*)(hp + 0);
        *(float4*)&av[4]  = *(const float4*)(hp + 4);
        *(float4*)&av[8]  = *(const float4*)(hp + 32);
        *(float4*)&av[12] = *(const float4*)(hp + 36);
        short8 Ah0, Ah1, Al0, Al1;
#pragma unroll
        for (int j = 0; j < 8; ++j) {
            unsigned short hi, lo;
            splitbf_t(av[j], hi, lo);     Ah0[j] = (short)hi; Al0[j] = (short)lo;
            splitbf_t(av[8+j], hi, lo);   Ah1[j] = (short)hi; Al1[j] = (short)lo;
        }
        f32x4 acc[4];
#pragma unroll
        for (int nt = 0; nt < 4; ++nt) {
            const unsigned short* ch = &W1h[(nt * 16 + m16) * KP_2 + quad * 8];
            const unsigned short* cl = &W1l[(nt * 16 + m16) * KP_2 + quad * 8];
            f32x4 a = {0.0f, 0.0f, 0.0f, 0.0f};
            short8 bh0 = *(const short8*)(ch +  0);
            short8 bh1 = *(const short8*)(ch + 32);
            short8 bl0 = *(const short8*)(cl +  0);
            short8 bl1 = *(const short8*)(cl + 32);
            a = __builtin_amdgcn_mfma_f32_16x16x32_bf16(Ah0, bh0, a, 0, 0, 0);
            a = __builtin_amdgcn_mfma_f32_16x16x32_bf16(Ah1, bh1, a, 0, 0, 0);
            a = __builtin_amdgcn_mfma_f32_16x16x32_bf16(Ah0, bl0, a, 0, 0, 0);
            a = __builtin_amdgcn_mfma_f32_16x16x32_bf16(Ah1, bl1, a, 0, 0, 0);
            a = __builtin_amdgcn_mfma_f32_16x16x32_bf16(Al0, bh0, a, 0, 0, 0);
            a = __builtin_amdgcn_mfma_f32_16x16x32_bf16(Al1, bh1, a, 0, 0, 0);
            acc[nt] = a;
        }
#pragma unroll
        for (int r4 = 0; r4 < 4; ++r4)
#pragma unroll
            for (int nt = 0; nt < 4; ++nt)
                tld[wave][(quad * 4 + r4) * 68 + nt * 16 + m16] =
                    silu_f(acc[nt][r4] + b1v[nt]);
        __syncthreads();
        float a2[16];
        *(float4*)&a2[0]  = *(const float4*)&tld[wave][m16 * 68 + quad * 8 + 0];
        *(float4*)&a2[4]  = *(const float4*)&tld[wave][m16 * 68 + quad * 8 + 4];
        *(float4*)&a2[8]  = *(const float4*)&tld[wave][m16 * 68 + quad * 8 + 32];
        *(float4*)&a2[12] = *(const float4*)&tld[wave][m16 * 68 + quad * 8 + 36];
        short8 A2h0, A2h1, A2l0, A2l1;
#pragma unroll
        for (int j = 0; j < 8; ++j) {
            unsigned short hi, lo;
            splitbf_t(a2[j], hi, lo);     A2h0[j] = (short)hi; A2l0[j] = (short)lo;
            splitbf_t(a2[8+j], hi, lo);   A2h1[j] = (short)hi; A2l1[j] = (short)lo;
        }
        f32x4 acc2[4];
#pragma unroll
        for (int nt = 0; nt < 4; ++nt) {
            const unsigned short* ch = &W2h[(nt * 16 + m16) * KP_2 + quad * 8];
            const unsigned short* cl = &W2l[(nt * 16 + m16) * KP_2 + quad * 8];
            f32x4 a = {0.0f, 0.0f, 0.0f, 0.0f};
            short8 bh0 = *(const short8*)(ch +  0);
            short8 bh1 = *(const short8*)(ch + 32);
            short8 bl0 = *(const short8*)(cl +  0);
            short8 bl1 = *(const short8*)(cl + 32);
            a = __builtin_amdgcn_mfma_f32_16x16x32_bf16(A2h0, bh0, a, 0, 0, 0);
            a = __builtin_amdgcn_mfma_f32_16x16x32_bf16(A2h1, bh1, a, 0, 0, 0);
            a = __builtin_amdgcn_mfma_f32_16x16x32_bf16(A2h0, bl0, a, 0, 0, 0);
            a = __builtin_amdgcn_mfma_f32_16x16x32_bf16(A2h1, bl1, a, 0, 0, 0);
            a = __builtin_amdgcn_mfma_f32_16x16x32_bf16(A2l0, bh0, a, 0, 0, 0);
            a = __builtin_amdgcn_mfma_f32_16x16x32_bf16(A2l1, bh1, a, 0, 0, 0);
            acc2[nt] = a;
        }
#pragma unroll
        for (int r4 = 0; r4 < 4; ++r4) {
            const int node = nb + quad * 4 + r4;
            const float nm = nmask[node];
#pragma unroll
            for (int nt = 0; nt < 4; ++nt)
                h[node * H + nt * 16 + m16] = (acc2[nt][r4] + b2v[nt]) * nm;
        }
        __syncthreads();
    }
}

// ---------------- pool + graph decoder + reaction aggregation ------------
__global__ __launch_bounds__(64) void k_graph(
        const float* __restrict__ h, const int* __restrict__ rid,
        const float* __restrict__ rsign,
        const float* __restrict__ W1, const float* __restrict__ b1,
        const float* __restrict__ W2, const float* __restrict__ b2,
        float* __restrict__ pred) {
    const int g = blockIdx.x;
    const int lane = threadIdx.x;
    float hgv = 0.0f;
#pragma unroll
    for (int m = 0; m < NN_PER_G; ++m)
        hgv += h[(g * NN_PER_G + m) * H + lane];
    __shared__ __align__(16) float hgs[64];
    hgs[lane] = hgv;
    __syncthreads();
    float acc = b1[lane];
#pragma unroll
    for (int k = 0; k < H; ++k)
        acc += hgs[k] * W1[k * H + lane];
    float part = silu_f(acc) * W2[lane];
#pragma unroll
    for (int off = 32; off > 0; off >>= 1)
        part += __shfl_down(part, off);
    if (lane == 0)
        atomAddF(&pred[rid[g]], (part + b2[0]) * rsign[g]);
}

extern "C" void kernel_launch(void* const* d_in, const int* in_sizes, int n_in,
                              void* d_out, int out_size, void* d_ws, size_t ws_size,
                              hipStream_t stream) {
    const float* h0      = (const float*)d_in[0];
    const float* pos     = (const float*)d_in[1];
    const int*   edges   = (const int*)d_in[2];
    const float* nmask   = (const float*)d_in[3];
    const float* emask   = (const float*)d_in[4];
    const int*   rid     = (const int*)d_in[5];
    const float* rsign   = (const float*)d_in[6];
    const float* emb_w   = (const float*)d_in[7];
    const float* emb_b   = (const float*)d_in[8];
    const float* edge_w1 = (const float*)d_in[9];
    const float* edge_b1 = (const float*)d_in[10];
    const float* edge_w2 = (const float*)d_in[11];
    const float* edge_b2 = (const float*)d_in[12];
    const float* node_w1 = (const float*)d_in[13];
    const float* node_b1 = (const float*)d_in[14];
    const float* node_w2 = (const float*)d_in[15];
    const float* node_b2 = (const float*)d_in[16];
    const float* dec_w1  = (const float*)d_in[17];
    const float* dec_b1  = (const float*)d_in[18];
    const float* dec_w2  = (const float*)d_in[19];
    const float* dec_b2  = (const float*)d_in[20];
    const float* g_w1    = (const float*)d_in[21];
    const float* g_b1    = (const float*)d_in[22];
    const float* g_w2    = (const float*)d_in[23];
    const float* g_b2    = (const float*)d_in[24];

    float* h      = (float*)d_ws;            // N*H
    float* agg    = h + N_NODES * H;         // N*H
    float* radial = agg + N_NODES * H;       // E
    float* PA     = radial + N_EDGES;        // N*H
    float* PB     = PA + N_NODES * H;        // N*H
    float* csrR   = PB + N_NODES * H;        // E
    float* csrM   = csrR + N_EDGES;          // E
    int*   csrP   = (int*)(csrM + N_EDGES);  // E
    int*   deg    = csrP + N_EDGES;          // N
    int*   off    = deg + N_NODES;           // N
    int*   bsum   = off + N_NODES;           // 256
    int*   bbase  = bsum + 256;              // 256
    int*   nstart = bbase + 256;             // N+1
    int*   cursor = nstart + N_NODES + 1;    // N
    float* pred   = (float*)d_out;

    hipMemsetAsync(d_out, 0, R_REACT * sizeof(float), stream);
    hipMemsetAsync(deg, 0, N_NODES * sizeof(int), stream);

    k_embed<<<(N_NODES * H) / 256, 256, 0, stream>>>(h0, emb_w, emb_b, h);
    k_radial<<<N_EDGES / 256, 256, 0, stream>>>(edges, pos, radial);
    k_hist<<<N_EDGES / 256, 256, 0, stream>>>(edges, deg);
    k_scan_blk<<<256, 128, 0, stream>>>(deg, off, bsum);
    k_scan_top<<<1, 256, 0, stream>>>(bsum, bbase);
    k_cursor<<<N_NODES / 256, 256, 0, stream>>>(off, bbase, nstart, cursor);
    k_fill<<<N_EDGES / 256, 256, 0, stream>>>(edges, radial, emask, cursor,
                                              csrP, csrR, csrM);

    for (int i = 0; i < L_LAYERS; ++i) {
        k_nodeproj_m<<<N_NODES / 128, 256, 0, stream>>>(
            h, edge_w1 + i * EIN * H, edge_b1 + i * H, PA, PB);
        k_edge7<<<N_NODES / NPBLK, 256, 0, stream>>>(
            PA, PB, nstart, csrP, csrR, csrM,
            edge_w1 + i * EIN * H,
            edge_w2 + i * H * H, edge_b2 + i * H, agg);
        k_node_m<<<N_NODES / 128, 256, 0, stream>>>(
            h, agg, h0,
            node_w1 + i * NIN * H, node_b1 + i * H,
            node_w2 + i * H * H,   node_b2 + i * H);
    }
    k_dec_m<<<N_NODES / 128, 256, 0, stream>>>(h, nmask, dec_w1, dec_b1,
                                               dec_w2, dec_b2);
    k_graph<<<G_GRAPHS, 64, 0, stream>>>(h, rid, rsign, g_w1, g_b1, g_w2,
                                         g_b2, pred);
}

// Round 10
// 563.008 us; speedup vs baseline: 1.2679x; 1.2679x over previous
//
#include <hip/hip_runtime.h>
#include <math.h>

#define N_NODES 32768
#define N_EDGES 491520
#define F_IN    11
#define H       64
#define G_GRAPHS 2048
#define NN_PER_G 16
#define R_REACT 1024
#define L_LAYERS 4
#define EIN     129   // 2H+1
#define NIN     139   // 2H+F
#define NPBLK   32    // nodes per k_edge6 block

typedef __attribute__((ext_vector_type(8))) short short8;
typedef __attribute__((ext_vector_type(4))) float f32x4;

__device__ __forceinline__ float silu_f(float x) {
    return x * __builtin_amdgcn_rcpf(1.0f + __expf(-x));
}
__device__ __forceinline__ void atomAddF(float* p, float v) {
    unsafeAtomicAdd(p, v);
}
__device__ __forceinline__ float bf2f(unsigned short b) {
    union { float f; unsigned u; } v; v.u = ((unsigned)b) << 16;
    return v.f;
}
__device__ __forceinline__ unsigned short f2bf(float x) {   // RNE
    union { float f; unsigned u; } v; v.f = x;
    unsigned r = v.u + 0x7FFFu + ((v.u >> 16) & 1u);
    return (unsigned short)(r >> 16);
}
// RNE split (weights, cold path)
__device__ __forceinline__ void splitbf(float x, unsigned short& hi, unsigned short& lo) {
    hi = f2bf(x);
    lo = f2bf(x - bf2f(hi));
}
// truncation split (hot path; R4-validated absmax 3e-5)
__device__ __forceinline__ void splitbf_t(float x, unsigned short& hi, unsigned short& lo) {
    union { float f; unsigned u; } v; v.f = x;
    hi = (unsigned short)(v.u >> 16);
    union { float f; unsigned u; } w; w.f = x - bf2f(hi);
    lo = (unsigned short)(w.u >> 16);
}

// ---------------- embed (+ fold deg=0) ----------------
__global__ __launch_bounds__(256) void k_embed(
        const float* __restrict__ h0, const float* __restrict__ emb_w,
        const float* __restrict__ emb_b, float* __restrict__ h,
        int* __restrict__ deg) {
    int tid = blockIdx.x * 256 + threadIdx.x;
    if (blockIdx.x < N_NODES / 256) deg[tid] = 0;   // 128 blocks cover N ints
    int n = tid >> 6, j = tid & 63;
    float acc = emb_b[j];
#pragma unroll
    for (int k = 0; k < F_IN; ++k)
        acc += h0[n * F_IN + k] * emb_w[k * H + j];
    h[tid] = acc;
}

// ---------------- radial ----------------
__global__ __launch_bounds__(256) void k_radial(
        const int* __restrict__ edges, const float* __restrict__ pos,
        float* __restrict__ radial) {
    int e = blockIdx.x * 256 + threadIdx.x;
    int r = edges[e], c = edges[N_EDGES + e];
    float dx = pos[r * 3 + 0] - pos[c * 3 + 0];
    float dy = pos[r * 3 + 1] - pos[c * 3 + 1];
    float dz = pos[r * 3 + 2] - pos[c * 3 + 2];
    radial[e] = dx * dx + dy * dy + dz * dz;
}

// ---------------- CSR build ----------------
__global__ __launch_bounds__(256) void k_hist(
        const int* __restrict__ edges, int* __restrict__ deg) {
    int e = blockIdx.x * 256 + threadIdx.x;
    atomicAdd(&deg[edges[e]], 1);
}

// single-block parallel exclusive scan of deg[N] -> nstart/cursor
__global__ __launch_bounds__(1024) void k_scan(
        const int* __restrict__ deg, int* __restrict__ nstart,
        int* __restrict__ cursor) {
    const int tid = threadIdx.x;
    const int lane = tid & 63, wv = tid >> 6;
    __shared__ int wsum[16];

    const int base = tid * 32;
    int local[32];
    int s = 0;
#pragma unroll
    for (int i = 0; i < 32; ++i) { local[i] = s; s += deg[base + i]; }

    // wave-level inclusive scan of per-thread totals
    int v = s;
#pragma unroll
    for (int off = 1; off < 64; off <<= 1) {
        int u = __shfl_up(v, off);
        if (lane >= off) v += u;
    }
    if (lane == 63) wsum[wv] = v;
    const int excl = v - s;
    __syncthreads();
    if (wv == 0 && lane < 16) {
        int w = wsum[lane];
        int vv = w;
#pragma unroll
        for (int off = 1; off < 16; off <<= 1) {
            int u = __shfl_up(vv, off);
            if (lane >= off) vv += u;
        }
        wsum[lane] = vv - w;   // exclusive
    }
    __syncthreads();
    const int bs = wsum[wv] + excl;
#pragma unroll
    for (int i = 0; i < 32; ++i) {
        int ns = bs + local[i];
        nstart[base + i] = ns;
        cursor[base + i] = ns;
    }
    if (tid == 0) nstart[N_NODES] = N_EDGES;
}

__global__ __launch_bounds__(256) void k_fill(
        const int* __restrict__ edges, const float* __restrict__ radial,
        const float* __restrict__ emask, int* __restrict__ cursor,
        int* __restrict__ csrP, float* __restrict__ csrR,
        float* __restrict__ csrM) {
    int e = blockIdx.x * 256 + threadIdx.x;
    int r = edges[e];
    int pos = atomicAdd(&cursor[r], 1);
    csrP[pos] = edges[N_EDGES + e] | ((r & (NPBLK - 1)) << 16);  // col | row_local
    csrR[pos] = radial[e];
    csrM[pos] = emask[e];
}

// ---------------- node projection via MFMA (2 tiles/wave, no spill) ------
__global__ __launch_bounds__(64, 1) void k_nodeproj_m(
        const float* __restrict__ h, const float* __restrict__ W1,
        const float* __restrict__ b1,
        float* __restrict__ PA, float* __restrict__ PB) {
    const int lane = threadIdx.x;
    const int quad = lane >> 4, m16 = lane & 15;

    short8 Bh[16], Bl[16];     // [nt*2+kf]; nt 0..3 -> PA cols, 4..7 -> PB
#pragma unroll
    for (int nt = 0; nt < 8; ++nt) {
#pragma unroll
        for (int kf = 0; kf < 2; ++kf) {
            short8 bh, bl;
#pragma unroll
            for (int j = 0; j < 8; ++j) {
                int row = (nt >= 4 ? 64 : 0) + kf * 32 + quad * 8 + j;
                float w = W1[row * H + (nt & 3) * 16 + m16];
                unsigned short hi, lo; splitbf(w, hi, lo);
                bh[j] = (short)hi; bl[j] = (short)lo;
            }
            Bh[nt * 2 + kf] = bh; Bl[nt * 2 + kf] = bl;
        }
    }
    float b1v[4];
#pragma unroll
    for (int nt = 0; nt < 4; ++nt) b1v[nt] = b1[nt * 16 + m16];

    for (int t = 0; t < 2; ++t) {
        const int nb = (blockIdx.x * 2 + t) * 16;
        const float* hp = h + (nb + m16) * H + quad * 8;
        float av[16];
        *(float4*)&av[0]  = *(const float4*)(hp + 0);
        *(float4*)&av[4]  = *(const float4*)(hp + 4);
        *(float4*)&av[8]  = *(const float4*)(hp + 32);
        *(float4*)&av[12] = *(const float4*)(hp + 36);
        short8 Ah0, Ah1, Al0, Al1;
#pragma unroll
        for (int j = 0; j < 8; ++j) {
            unsigned short hi, lo;
            splitbf_t(av[j], hi, lo);     Ah0[j] = (short)hi; Al0[j] = (short)lo;
            splitbf_t(av[8 + j], hi, lo); Ah1[j] = (short)hi; Al1[j] = (short)lo;
        }
        f32x4 acc[8];
#pragma unroll
        for (int nt = 0; nt < 8; ++nt) {
            f32x4 a = {0.0f, 0.0f, 0.0f, 0.0f};
            a = __builtin_amdgcn_mfma_f32_16x16x32_bf16(Ah0, Bh[nt*2+0], a, 0, 0, 0);
            a = __builtin_amdgcn_mfma_f32_16x16x32_bf16(Ah1, Bh[nt*2+1], a, 0, 0, 0);
            a = __builtin_amdgcn_mfma_f32_16x16x32_bf16(Ah0, Bl[nt*2+0], a, 0, 0, 0);
            a = __builtin_amdgcn_mfma_f32_16x16x32_bf16(Ah1, Bl[nt*2+1], a, 0, 0, 0);
            a = __builtin_amdgcn_mfma_f32_16x16x32_bf16(Al0, Bh[nt*2+0], a, 0, 0, 0);
            a = __builtin_amdgcn_mfma_f32_16x16x32_bf16(Al1, Bh[nt*2+1], a, 0, 0, 0);
            acc[nt] = a;
        }
#pragma unroll
        for (int r4 = 0; r4 < 4; ++r4) {
            const int node = nb + quad * 4 + r4;
#pragma unroll
            for (int nt = 0; nt < 4; ++nt)
                PA[node * H + nt * 16 + m16] = acc[nt][r4] + b1v[nt];
#pragma unroll
            for (int nt = 4; nt < 8; ++nt)
                PB[node * H + (nt - 4) * 16 + m16] = acc[nt][r4];
        }
    }
}

// ---------------- edge MLP: CSR + prefetch + LDS run-reduced agg ---------
__global__ __launch_bounds__(256, 2) void k_edge6(
        const float* __restrict__ PA, const float* __restrict__ PB,
        const int* __restrict__ nstart, const int* __restrict__ csrP,
        const float* __restrict__ csrR, const float* __restrict__ csrM,
        const float* __restrict__ W1,   // only row 128 (w1c) used
        const float* __restrict__ W2, const float* __restrict__ b2,
        float* __restrict__ agg) {
    const int tid = threadIdx.x;
    const int lane = tid & 63, wave = tid >> 6;
    const int quad = lane >> 4, m16 = lane & 15;
    const int n0 = blockIdx.x * NPBLK;

    __shared__ float aggld[NPBLK * 68];
    for (int i = tid; i < NPBLK * 68; i += 256) aggld[i] = 0.0f;

    short8 Bh[8], Bl[8];
#pragma unroll
    for (int nt = 0; nt < 4; ++nt) {
#pragma unroll
        for (int kf = 0; kf < 2; ++kf) {
            short8 bh, bl;
#pragma unroll
            for (int j = 0; j < 8; ++j) {
                float w = W2[(kf * 32 + quad * 8 + j) * H + nt * 16 + m16];
                unsigned short hi, lo; splitbf(w, hi, lo);
                bh[j] = (short)hi; bl[j] = (short)lo;
            }
            Bh[nt * 2 + kf] = bh; Bl[nt * 2 + kf] = bl;
        }
    }
    float w1cr[16];
#pragma unroll
    for (int i = 0; i < 16; ++i) {
        int k = (i < 8) ? (quad * 8 + i) : (32 + quad * 8 + (i - 8));
        w1cr[i] = W1[128 * H + k];
    }
    float b2v[4];
#pragma unroll
    for (int nt = 0; nt < 4; ++nt) b2v[nt] = b2[nt * 16 + m16];

    const int start = nstart[n0];
    const int end   = nstart[n0 + NPBLK];
    __syncthreads();

    const int ntiles = (end - start + 15) >> 4;

    float radA = 0.0f, avA[16], bvA[16];
    int rlA = 0;
    int rlqA[4]; float mkqA[4];

    int t = wave;
    bool haveA = t < ntiles;
    if (haveA) {
        const int idx = start + t * 16 + m16;
        const int ss = min(idx, N_EDGES - 1);
        const int pk = csrP[ss];
        radA = csrR[ss];
        const int c = pk & 0xFFFF;
        rlA = pk >> 16;
        const int sb = start + t * 16 + quad * 4;
#pragma unroll
        for (int r4 = 0; r4 < 4; ++r4) {
            int s = sb + r4, s2 = min(s, N_EDGES - 1);
            rlqA[r4] = csrP[s2] >> 16;
            mkqA[r4] = (s < end) ? csrM[s2] : 0.0f;
        }
        const float* par = PA + (n0 + rlA) * H + quad * 8;
        const float* pbr = PB + c * H + quad * 8;
        *(float4*)&avA[0]  = *(const float4*)(par + 0);
        *(float4*)&avA[4]  = *(const float4*)(par + 4);
        *(float4*)&avA[8]  = *(const float4*)(par + 32);
        *(float4*)&avA[12] = *(const float4*)(par + 36);
        *(float4*)&bvA[0]  = *(const float4*)(pbr + 0);
        *(float4*)&bvA[4]  = *(const float4*)(pbr + 4);
        *(float4*)&bvA[8]  = *(const float4*)(pbr + 32);
        *(float4*)&bvA[12] = *(const float4*)(pbr + 36);
    }

    while (haveA) {
        const int tn = t + 4;
        const bool haveB = tn < ntiles;
        float radB = 0.0f, bvB[16];
        int rlB = 0;
        int rlqB[4]; float mkqB[4];
        if (haveB) {
            const int idx = start + tn * 16 + m16;
            const int ss = min(idx, N_EDGES - 1);
            const int pk = csrP[ss];
            radB = csrR[ss];
            const int c = pk & 0xFFFF;
            rlB = pk >> 16;
            const int sb = start + tn * 16 + quad * 4;
#pragma unroll
            for (int r4 = 0; r4 < 4; ++r4) {
                int s = sb + r4, s2 = min(s, N_EDGES - 1);
                rlqB[r4] = csrP[s2] >> 16;
                mkqB[r4] = (s < end) ? csrM[s2] : 0.0f;
            }
            const float* pbr = PB + c * H + quad * 8;
            *(float4*)&bvB[0]  = *(const float4*)(pbr + 0);
            *(float4*)&bvB[4]  = *(const float4*)(pbr + 4);
            *(float4*)&bvB[8]  = *(const float4*)(pbr + 32);
            *(float4*)&bvB[12] = *(const float4*)(pbr + 36);
        }

        short8 Ah0, Ah1, Al0, Al1;
#pragma unroll
        for (int i = 0; i < 8; ++i) {
            unsigned short hi, lo;
            splitbf_t(silu_f(avA[i] + bvA[i] + radA * w1cr[i]), hi, lo);
            Ah0[i] = (short)hi; Al0[i] = (short)lo;
            splitbf_t(silu_f(avA[8+i] + bvA[8+i] + radA * w1cr[8+i]), hi, lo);
            Ah1[i] = (short)hi; Al1[i] = (short)lo;
        }
        f32x4 acc[4];
#pragma unroll
        for (int nt = 0; nt < 4; ++nt) {
            f32x4 a = {0.0f, 0.0f, 0.0f, 0.0f};
            a = __builtin_amdgcn_mfma_f32_16x16x32_bf16(Ah0, Bh[nt*2+0], a, 0, 0, 0);
            a = __builtin_amdgcn_mfma_f32_16x16x32_bf16(Ah1, Bh[nt*2+1], a, 0, 0, 0);
            a = __builtin_amdgcn_mfma_f32_16x16x32_bf16(Ah0, Bl[nt*2+0], a, 0, 0, 0);
            a = __builtin_amdgcn_mfma_f32_16x16x32_bf16(Ah1, Bl[nt*2+1], a, 0, 0, 0);
            a = __builtin_amdgcn_mfma_f32_16x16x32_bf16(Al0, Bh[nt*2+0], a, 0, 0, 0);
            a = __builtin_amdgcn_mfma_f32_16x16x32_bf16(Al1, Bh[nt*2+1], a, 0, 0, 0);
            acc[nt] = a;
        }

#pragma unroll
        for (int nt = 0; nt < 4; ++nt) {
            float oo[4];
#pragma unroll
            for (int r4 = 0; r4 < 4; ++r4)
                oo[r4] = silu_f(acc[nt][r4] + b2v[nt]) * mkqA[r4];
            int cur = rlqA[0]; float s = oo[0];
#pragma unroll
            for (int r4 = 1; r4 < 4; ++r4) {
                if (rlqA[r4] == cur) { s += oo[r4]; }
                else {
                    atomicAdd(&aggld[cur * 68 + nt * 16 + m16], s);
                    cur = rlqA[r4]; s = oo[r4];
                }
            }
            atomicAdd(&aggld[cur * 68 + nt * 16 + m16], s);
        }

        if (haveB) {
            radA = radB; rlA = rlB;
#pragma unroll
            for (int r4 = 0; r4 < 4; ++r4) { rlqA[r4] = rlqB[r4]; mkqA[r4] = mkqB[r4]; }
            const float* par = PA + (n0 + rlA) * H + quad * 8;
            *(float4*)&avA[0]  = *(const float4*)(par + 0);
            *(float4*)&avA[4]  = *(const float4*)(par + 4);
            *(float4*)&avA[8]  = *(const float4*)(par + 32);
            *(float4*)&avA[12] = *(const float4*)(par + 36);
#pragma unroll
            for (int i = 0; i < 16; ++i) bvA[i] = bvB[i];
        }
        t = tn; haveA = haveB;
    }

    __syncthreads();
#pragma unroll
    for (int i = tid; i < NPBLK * 16; i += 256) {
        int n = i >> 4, cb = (i & 15) << 2;
        *(float4*)&agg[(n0 + n) * H + cb] = *(const float4*)&aggld[n * 68 + cb];
    }
}

// ---------------- node MLP via MFMA (2 tiles/wave, no spill) -------------
__global__ __launch_bounds__(64, 1) void k_node_m(
        float* __restrict__ h, const float* __restrict__ agg,
        const float* __restrict__ h0,
        const float* __restrict__ W1, const float* __restrict__ b1,
        const float* __restrict__ W2, const float* __restrict__ b2) {
    const int lane = threadIdx.x;
    const int quad = lane >> 4, m16 = lane & 15;

    short8 B1h[20], B1l[20];   // [nt*5+kf], rows 0..159 (pad >=139 with 0)
#pragma unroll
    for (int nt = 0; nt < 4; ++nt) {
#pragma unroll
        for (int kf = 0; kf < 5; ++kf) {
            short8 bh, bl;
#pragma unroll
            for (int j = 0; j < 8; ++j) {
                int row = kf * 32 + quad * 8 + j;
                float w = (row < NIN) ? W1[row * H + nt * 16 + m16] : 0.0f;
                unsigned short hi, lo; splitbf(w, hi, lo);
                bh[j] = (short)hi; bl[j] = (short)lo;
            }
            B1h[nt * 5 + kf] = bh; B1l[nt * 5 + kf] = bl;
        }
    }
    short8 B2h[8], B2l[8];
#pragma unroll
    for (int nt = 0; nt < 4; ++nt) {
#pragma unroll
        for (int kf = 0; kf < 2; ++kf) {
            short8 bh, bl;
#pragma unroll
            for (int j = 0; j < 8; ++j) {
                float w = W2[(kf * 32 + quad * 8 + j) * H + nt * 16 + m16];
                unsigned short hi, lo; splitbf(w, hi, lo);
                bh[j] = (short)hi; bl[j] = (short)lo;
            }
            B2h[nt * 2 + kf] = bh; B2l[nt * 2 + kf] = bl;
        }
    }
    float b1v[4], b2v[4];
#pragma unroll
    for (int nt = 0; nt < 4; ++nt) {
        b1v[nt] = b1[nt * 16 + m16];
        b2v[nt] = b2[nt * 16 + m16];
    }

    __shared__ float tld[16 * 68];   // stride 68: no 4-way bank conflict

    for (int t = 0; t < 2; ++t) {
        const int nb = (blockIdx.x * 2 + t) * 16;
        float a1[5][8];
        const float* hp = h + (nb + m16) * H + quad * 8;
        const float* ap = agg + (nb + m16) * H + quad * 8;
        *(float4*)&a1[0][0] = *(const float4*)(hp + 0);
        *(float4*)&a1[0][4] = *(const float4*)(hp + 4);
        *(float4*)&a1[1][0] = *(const float4*)(hp + 32);
        *(float4*)&a1[1][4] = *(const float4*)(hp + 36);
        *(float4*)&a1[2][0] = *(const float4*)(ap + 0);
        *(float4*)&a1[2][4] = *(const float4*)(ap + 4);
        *(float4*)&a1[3][0] = *(const float4*)(ap + 32);
        *(float4*)&a1[3][4] = *(const float4*)(ap + 36);
        const float* h0p = h0 + (nb + m16) * F_IN;
#pragma unroll
        for (int j = 0; j < 8; ++j) {
            int kk = quad * 8 + j;
            a1[4][j] = (kk < F_IN) ? h0p[kk] : 0.0f;
        }
        short8 A1h[5], A1l[5];
#pragma unroll
        for (int kf = 0; kf < 5; ++kf) {
            short8 ah, al;
#pragma unroll
            for (int j = 0; j < 8; ++j) {
                unsigned short hi, lo; splitbf_t(a1[kf][j], hi, lo);
                ah[j] = (short)hi; al[j] = (short)lo;
            }
            A1h[kf] = ah; A1l[kf] = al;
        }
        f32x4 acc[4];
#pragma unroll
        for (int nt = 0; nt < 4; ++nt) {
            f32x4 a = {0.0f, 0.0f, 0.0f, 0.0f};
#pragma unroll
            for (int kf = 0; kf < 5; ++kf)
                a = __builtin_amdgcn_mfma_f32_16x16x32_bf16(A1h[kf], B1h[nt*5+kf], a, 0, 0, 0);
#pragma unroll
            for (int kf = 0; kf < 5; ++kf)
                a = __builtin_amdgcn_mfma_f32_16x16x32_bf16(A1l[kf], B1h[nt*5+kf], a, 0, 0, 0);
#pragma unroll
            for (int kf = 0; kf < 5; ++kf)
                a = __builtin_amdgcn_mfma_f32_16x16x32_bf16(A1h[kf], B1l[nt*5+kf], a, 0, 0, 0);
            acc[nt] = a;
        }
#pragma unroll
        for (int r4 = 0; r4 < 4; ++r4)
#pragma unroll
            for (int nt = 0; nt < 4; ++nt)
                tld[(quad * 4 + r4) * 68 + nt * 16 + m16] =
                    silu_f(acc[nt][r4] + b1v[nt]);
        __syncthreads();
        float a2[16];
        *(float4*)&a2[0]  = *(const float4*)&tld[m16 * 68 + quad * 8 + 0];
        *(float4*)&a2[4]  = *(const float4*)&tld[m16 * 68 + quad * 8 + 4];
        *(float4*)&a2[8]  = *(const float4*)&tld[m16 * 68 + quad * 8 + 32];
        *(float4*)&a2[12] = *(const float4*)&tld[m16 * 68 + quad * 8 + 36];
        short8 A2h0, A2h1, A2l0, A2l1;
#pragma unroll
        for (int j = 0; j < 8; ++j) {
            unsigned short hi, lo;
            splitbf_t(a2[j], hi, lo);     A2h0[j] = (short)hi; A2l0[j] = (short)lo;
            splitbf_t(a2[8+j], hi, lo);   A2h1[j] = (short)hi; A2l1[j] = (short)lo;
        }
        f32x4 acc2[4];
#pragma unroll
        for (int nt = 0; nt < 4; ++nt) {
            f32x4 a = {0.0f, 0.0f, 0.0f, 0.0f};
            a = __builtin_amdgcn_mfma_f32_16x16x32_bf16(A2h0, B2h[nt*2+0], a, 0, 0, 0);
            a = __builtin_amdgcn_mfma_f32_16x16x32_bf16(A2h1, B2h[nt*2+1], a, 0, 0, 0);
            a = __builtin_amdgcn_mfma_f32_16x16x32_bf16(A2h0, B2l[nt*2+0], a, 0, 0, 0);
            a = __builtin_amdgcn_mfma_f32_16x16x32_bf16(A2h1, B2l[nt*2+1], a, 0, 0, 0);
            a = __builtin_amdgcn_mfma_f32_16x16x32_bf16(A2l0, B2h[nt*2+0], a, 0, 0, 0);
            a = __builtin_amdgcn_mfma_f32_16x16x32_bf16(A2l1, B2h[nt*2+1], a, 0, 0, 0);
            acc2[nt] = a;
        }
#pragma unroll
        for (int r4 = 0; r4 < 4; ++r4) {
            const int node = nb + quad * 4 + r4;
#pragma unroll
            for (int nt = 0; nt < 4; ++nt)
                h[node * H + nt * 16 + m16] = acc2[nt][r4] + b2v[nt];
        }
        __syncthreads();
    }
}

// ---------------- node decoder via MFMA (2 tiles/wave) + pred=0 ----------
__global__ __launch_bounds__(64, 1) void k_dec_m(
        float* __restrict__ h, const float* __restrict__ nmask,
        const float* __restrict__ W1, const float* __restrict__ b1,
        const float* __restrict__ W2, const float* __restrict__ b2,
        float* __restrict__ pred) {
    const int lane = threadIdx.x;
    const int quad = lane >> 4, m16 = lane & 15;

    if (blockIdx.x < R_REACT / 64) pred[blockIdx.x * 64 + lane] = 0.0f;

    short8 B1h[8], B1l[8], B2h[8], B2l[8];
#pragma unroll
    for (int nt = 0; nt < 4; ++nt) {
#pragma unroll
        for (int kf = 0; kf < 2; ++kf) {
            short8 bh1, bl1, bh2, bl2;
#pragma unroll
            for (int j = 0; j < 8; ++j) {
                int row = kf * 32 + quad * 8 + j;
                unsigned short hi, lo;
                splitbf(W1[row * H + nt * 16 + m16], hi, lo);
                bh1[j] = (short)hi; bl1[j] = (short)lo;
                splitbf(W2[row * H + nt * 16 + m16], hi, lo);
                bh2[j] = (short)hi; bl2[j] = (short)lo;
            }
            B1h[nt*2+kf] = bh1; B1l[nt*2+kf] = bl1;
            B2h[nt*2+kf] = bh2; B2l[nt*2+kf] = bl2;
        }
    }
    float b1v[4], b2v[4];
#pragma unroll
    for (int nt = 0; nt < 4; ++nt) {
        b1v[nt] = b1[nt * 16 + m16];
        b2v[nt] = b2[nt * 16 + m16];
    }
    __shared__ float tld[16 * 68];

    for (int t = 0; t < 2; ++t) {
        const int nb = (blockIdx.x * 2 + t) * 16;
        const float* hp = h + (nb + m16) * H + quad * 8;
        float av[16];
        *(float4*)&av[0]  = *(const float4*)(hp + 0);
        *(float4*)&av[4]  = *(const float4*)(hp + 4);
        *(float4*)&av[8]  = *(const float4*)(hp + 32);
        *(float4*)&av[12] = *(const float4*)(hp + 36);
        short8 Ah0, Ah1, Al0, Al1;
#pragma unroll
        for (int j = 0; j < 8; ++j) {
            unsigned short hi, lo;
            splitbf_t(av[j], hi, lo);     Ah0[j] = (short)hi; Al0[j] = (short)lo;
            splitbf_t(av[8+j], hi, lo);   Ah1[j] = (short)hi; Al1[j] = (short)lo;
        }
        f32x4 acc[4];
#pragma unroll
        for (int nt = 0; nt < 4; ++nt) {
            f32x4 a = {0.0f, 0.0f, 0.0f, 0.0f};
            a = __builtin_amdgcn_mfma_f32_16x16x32_bf16(Ah0, B1h[nt*2+0], a, 0, 0, 0);
            a = __builtin_amdgcn_mfma_f32_16x16x32_bf16(Ah1, B1h[nt*2+1], a, 0, 0, 0);
            a = __builtin_amdgcn_mfma_f32_16x16x32_bf16(Ah0, B1l[nt*2+0], a, 0, 0, 0);
            a = __builtin_amdgcn_mfma_f32_16x16x32_bf16(Ah1, B1l[nt*2+1], a, 0, 0, 0);
            a = __builtin_amdgcn_mfma_f32_16x16x32_bf16(Al0, B1h[nt*2+0], a, 0, 0, 0);
            a = __builtin_amdgcn_mfma_f32_16x16x32_bf16(Al1, B1h[nt*2+1], a, 0, 0, 0);
            acc[nt] = a;
        }
#pragma unroll
        for (int r4 = 0; r4 < 4; ++r4)
#pragma unroll
            for (int nt = 0; nt < 4; ++nt)
                tld[(quad * 4 + r4) * 68 + nt * 16 + m16] =
                    silu_f(acc[nt][r4] + b1v[nt]);
        __syncthreads();
        float a2[16];
        *(float4*)&a2[0]  = *(const float4*)&tld[m16 * 68 + quad * 8 + 0];
        *(float4*)&a2[4]  = *(const float4*)&tld[m16 * 68 + quad * 8 + 4];
        *(float4*)&a2[8]  = *(const float4*)&tld[m16 * 68 + quad * 8 + 32];
        *(float4*)&a2[12] = *(const float4*)&tld[m16 * 68 + quad * 8 + 36];
        short8 A2h0, A2h1, A2l0, A2l1;
#pragma unroll
        for (int j = 0; j < 8; ++j) {
            unsigned short hi, lo;
            splitbf_t(a2[j], hi, lo);     A2h0[j] = (short)hi; A2l0[j] = (short)lo;
            splitbf_t(a2[8+j], hi, lo);   A2h1[j] = (short)hi; A2l1[j] = (short)lo;
        }
        f32x4 acc2[4];
#pragma unroll
        for (int nt = 0; nt < 4; ++nt) {
            f32x4 a = {0.0f, 0.0f, 0.0f, 0.0f};
            a = __builtin_amdgcn_mfma_f32_16x16x32_bf16(A2h0, B2h[nt*2+0], a, 0, 0, 0);
            a = __builtin_amdgcn_mfma_f32_16x16x32_bf16(A2h1, B2h[nt*2+1], a, 0, 0, 0);
            a = __builtin_amdgcn_mfma_f32_16x16x32_bf16(A2h0, B2l[nt*2+0], a, 0, 0, 0);
            a = __builtin_amdgcn_mfma_f32_16x16x32_bf16(A2h1, B2l[nt*2+1], a, 0, 0, 0);
            a = __builtin_amdgcn_mfma_f32_16x16x32_bf16(A2l0, B2h[nt*2+0], a, 0, 0, 0);
            a = __builtin_amdgcn_mfma_f32_16x16x32_bf16(A2l1, B2h[nt*2+1], a, 0, 0, 0);
            acc2[nt] = a;
        }
#pragma unroll
        for (int r4 = 0; r4 < 4; ++r4) {
            const int node = nb + quad * 4 + r4;
            const float nm = nmask[node];
#pragma unroll
            for (int nt = 0; nt < 4; ++nt)
                h[node * H + nt * 16 + m16] = (acc2[nt][r4] + b2v[nt]) * nm;
        }
        __syncthreads();
    }
}

// ---------------- pool + graph decoder + reaction aggregation ------------
__global__ __launch_bounds__(64) void k_graph(
        const float* __restrict__ h, const int* __restrict__ rid,
        const float* __restrict__ rsign,
        const float* __restrict__ W1, const float* __restrict__ b1,
        const float* __restrict__ W2, const float* __restrict__ b2,
        float* __restrict__ pred) {
    const int g = blockIdx.x;
    const int lane = threadIdx.x;
    float hgv = 0.0f;
#pragma unroll
    for (int m = 0; m < NN_PER_G; ++m)
        hgv += h[(g * NN_PER_G + m) * H + lane];
    __shared__ __align__(16) float hgs[64];
    hgs[lane] = hgv;
    __syncthreads();
    float acc = b1[lane];
#pragma unroll
    for (int k = 0; k < H; ++k)
        acc += hgs[k] * W1[k * H + lane];
    float part = silu_f(acc) * W2[lane];
#pragma unroll
    for (int off = 32; off > 0; off >>= 1)
        part += __shfl_down(part, off);
    if (lane == 0)
        atomAddF(&pred[rid[g]], (part + b2[0]) * rsign[g]);
}

extern "C" void kernel_launch(void* const* d_in, const int* in_sizes, int n_in,
                              void* d_out, int out_size, void* d_ws, size_t ws_size,
                              hipStream_t stream) {
    const float* h0      = (const float*)d_in[0];
    const float* pos     = (const float*)d_in[1];
    const int*   edges   = (const int*)d_in[2];
    const float* nmask   = (const float*)d_in[3];
    const float* emask   = (const float*)d_in[4];
    const int*   rid     = (const int*)d_in[5];
    const float* rsign   = (const float*)d_in[6];
    const float* emb_w   = (const float*)d_in[7];
    const float* emb_b   = (const float*)d_in[8];
    const float* edge_w1 = (const float*)d_in[9];
    const float* edge_b1 = (const float*)d_in[10];
    const float* edge_w2 = (const float*)d_in[11];
    const float* edge_b2 = (const float*)d_in[12];
    const float* node_w1 = (const float*)d_in[13];
    const float* node_b1 = (const float*)d_in[14];
    const float* node_w2 = (const float*)d_in[15];
    const float* node_b2 = (const float*)d_in[16];
    const float* dec_w1  = (const float*)d_in[17];
    const float* dec_b1  = (const float*)d_in[18];
    const float* dec_w2  = (const float*)d_in[19];
    const float* dec_b2  = (const float*)d_in[20];
    const float* g_w1    = (const float*)d_in[21];
    const float* g_b1    = (const float*)d_in[22];
    const float* g_w2    = (const float*)d_in[23];
    const float* g_b2    = (const float*)d_in[24];

    float* h      = (float*)d_ws;            // N*H
    float* agg    = h + N_NODES * H;         // N*H
    float* radial = agg + N_NODES * H;       // E
    float* PA     = radial + N_EDGES;        // N*H
    float* PB     = PA + N_NODES * H;        // N*H
    float* csrR   = PB + N_NODES * H;        // E
    float* csrM   = csrR + N_EDGES;          // E
    int*   csrP   = (int*)(csrM + N_EDGES);  // E
    int*   deg    = csrP + N_EDGES;          // N
    int*   nstart = deg + N_NODES;           // N+1
    int*   cursor = nstart + N_NODES + 1;    // N
    float* pred   = (float*)d_out;

    k_embed<<<(N_NODES * H) / 256, 256, 0, stream>>>(h0, emb_w, emb_b, h, deg);
    k_radial<<<N_EDGES / 256, 256, 0, stream>>>(edges, pos, radial);
    k_hist<<<N_EDGES / 256, 256, 0, stream>>>(edges, deg);
    k_scan<<<1, 1024, 0, stream>>>(deg, nstart, cursor);
    k_fill<<<N_EDGES / 256, 256, 0, stream>>>(edges, radial, emask, cursor,
                                              csrP, csrR, csrM);

    for (int i = 0; i < L_LAYERS; ++i) {
        k_nodeproj_m<<<N_NODES / 32, 64, 0, stream>>>(
            h, edge_w1 + i * EIN * H, edge_b1 + i * H, PA, PB);
        k_edge6<<<N_NODES / NPBLK, 256, 0, stream>>>(
            PA, PB, nstart, csrP, csrR, csrM,
            edge_w1 + i * EIN * H,
            edge_w2 + i * H * H, edge_b2 + i * H, agg);
        k_node_m<<<N_NODES / 32, 64, 0, stream>>>(
            h, agg, h0,
            node_w1 + i * NIN * H, node_b1 + i * H,
            node_w2 + i * H * H,   node_b2 + i * H);
    }
    k_dec_m<<<N_NODES / 32, 64, 0, stream>>>(h, nmask, dec_w1, dec_b1,
                                             dec_w2, dec_b2, pred);
    k_graph<<<G_GRAPHS, 64, 0, stream>>>(h, rid, rsign, g_w1, g_b1, g_w2,
                                         g_b2, pred);
}